// Round 4
// baseline (94.858 us; speedup 1.0000x reference)
//
#include <hip/hip_runtime.h>
#include <hip/hip_bf16.h>
#include <math.h>

#define B 4096
#define D 1024
#define BM 128
#define BN 128
#define BK 32
#define NKT (D / BK)  // 32 K-tiles
#define NBLK (B / BM)  // 32 row/col blocks
#define NTRI (NBLK * (NBLK + 1) / 2)  // 528 upper-tri blocks

#define CS_BLOCKS 256
#define CS_ROWS (B / CS_BLOCKS)  // 16

typedef float f32x4 __attribute__((ext_vector_type(4)));
typedef short s16x8 __attribute__((ext_vector_type(8)));

__device__ inline void gload_lds16(const void* g, void* l) {
    __builtin_amdgcn_global_load_lds(
        (const __attribute__((address_space(1))) void*)g,
        (__attribute__((address_space(3))) void*)l, 16, 0, 0);
}

// K0: fused fp32->bf16 convert + label-masked partial column sums.
__global__ __launch_bounds__(256) void prep_kernel(const float* __restrict__ E,
                                                   const int* __restrict__ labels,
                                                   unsigned short* __restrict__ Ebf,
                                                   float* __restrict__ partial) {
    int tid = threadIdx.x;
    int b = blockIdx.x;
    float4 acc = {0.f, 0.f, 0.f, 0.f};
    int r0 = b * CS_ROWS;
#pragma unroll 4
    for (int j = r0; j < r0 + CS_ROWS; ++j) {
        float4 v = *(const float4*)(E + (size_t)j * D + tid * 4);
        __hip_bfloat16 b0 = __float2bfloat16(v.x);
        __hip_bfloat16 b1 = __float2bfloat16(v.y);
        __hip_bfloat16 b2 = __float2bfloat16(v.z);
        __hip_bfloat16 b3 = __float2bfloat16(v.w);
        ushort4 o;
        o.x = *reinterpret_cast<unsigned short*>(&b0);
        o.y = *reinterpret_cast<unsigned short*>(&b1);
        o.z = *reinterpret_cast<unsigned short*>(&b2);
        o.w = *reinterpret_cast<unsigned short*>(&b3);
        *reinterpret_cast<ushort4*>(&Ebf[(size_t)j * D + tid * 4]) = o;
        if (labels[j] == 0) {
            acc.x += v.x;
            acc.y += v.y;
            acc.z += v.z;
            acc.w += v.w;
        }
    }
    *(float4*)(partial + (size_t)b * D + tid * 4) = acc;
}

// K1: reduce partials -> s[d]; also zero denomsum.
__global__ __launch_bounds__(256) void colsum_reduce_kernel(const float* __restrict__ partial,
                                                            float* __restrict__ s,
                                                            float* __restrict__ denomsum) {
    int d = blockIdx.x * 256 + threadIdx.x;
    float acc = 0.f;
    for (int p = 0; p < CS_BLOCKS; ++p) acc += partial[(size_t)p * D + d];
    s[d] = acc;
    for (int i = d; i < B; i += D) denomsum[i] = 0.f;
}

// K2: per-row selfdot = <e_i,e_i>, rawpos = <e_i, s>
__global__ __launch_bounds__(256) void rowstats_kernel(const float* __restrict__ E,
                                                       const float* __restrict__ s,
                                                       float* __restrict__ selfdot,
                                                       float* __restrict__ rawpos) {
    int wave = threadIdx.x >> 6;
    int lane = threadIdx.x & 63;
    int row = blockIdx.x * 4 + wave;
    const float4* er = (const float4*)(E + (size_t)row * D);
    const float4* s4 = (const float4*)s;
    float sd = 0.f, pp = 0.f;
    for (int it = 0; it < D / 4 / 64; ++it) {
        int k4 = it * 64 + lane;
        float4 v = er[k4];
        float4 w = s4[k4];
        sd += v.x * v.x + v.y * v.y + v.z * v.z + v.w * v.w;
        pp += v.x * w.x + v.y * w.y + v.z * w.z + v.w * w.w;
    }
    for (int m = 32; m; m >>= 1) {
        sd += __shfl_xor(sd, m, 64);
        pp += __shfl_xor(pp, m, 64);
    }
    if (lane == 0) {
        selfdot[row] = sd;
        rawpos[row] = pp;
    }
}

// K3: symmetric flash kernel, 2-deep counted-vmcnt double-buffered pipeline.
// Off-diagonal block (bi<bj): row-sums -> denomsum[rows], col-sums -> denomsum[cols].
// Diagonal block (bi==bj): mask diagonal, row-sums only.
__global__ __launch_bounds__(256) void simexp_sym_kernel(const unsigned short* __restrict__ Ebf,
                                                         float* __restrict__ denomsum) {
    __shared__ short As[2][BM * BK];
    __shared__ short Bs[2][BN * BK];
    const int tid = threadIdx.x;
    const int lane = tid & 63;
    const int wave = tid >> 6;
    const int wr = wave >> 1, wc = wave & 1;

    // map linear block id -> upper-triangular (bi, bj), bj >= bi
    int t = blockIdx.x;
    int bi = 0;
    int rowcnt = NBLK;
    while (t >= rowcnt) {
        t -= rowcnt;
        bi++;
        rowcnt--;
    }
    int bj = bi + t;
    const bool isDiag = (bi == bj);
    const int rowBase = bi * BM;
    const int colBase = bj * BN;

    f32x4 acc[4][4];
#pragma unroll
    for (int i = 0; i < 4; i++)
#pragma unroll
        for (int j = 0; j < 4; j++) acc[i][j] = (f32x4)(0.f);

    const short* gbase = (const short*)Ebf;

    // stage K-tile kt into buffer buf: 4 gload_lds (A x2, B x2) per thread
    auto stage = [&](int kt, int buf) {
#pragma unroll
        for (int q = 0; q < 2; ++q) {
            int c = wave * 128 + q * 64 + lane;  // 16B chunk index in tile
            int r = c >> 2;                      // tile row
            int c8 = (c & 3) * 8;                // element offset within row
            const short* ga = gbase + (size_t)(rowBase + r) * D + kt * BK + c8;
            const short* gb = gbase + (size_t)(colBase + r) * D + kt * BK + c8;
            gload_lds16(ga, &As[buf][c * 8]);
            gload_lds16(gb, &Bs[buf][c * 8]);
        }
    };

    // prologue: 2 K-tiles in flight (8 loads outstanding)
    stage(0, 0);
    stage(1, 1);

    const int ko = (lane >> 4) * 8;
    const int lrow = lane & 15;

    for (int kt = 0; kt < NKT; ++kt) {
        int buf = kt & 1;
        // wait only this K-tile's 4 loads; keep next tile's 4 in flight
        if (kt < NKT - 1) {
            asm volatile("s_waitcnt vmcnt(4)" ::: "memory");
        } else {
            asm volatile("s_waitcnt vmcnt(0)" ::: "memory");
        }
        __builtin_amdgcn_s_barrier();

        s16x8 afrag[4], bfrag[4];
#pragma unroll
        for (int mi = 0; mi < 4; ++mi)
            afrag[mi] = *(const s16x8*)&As[buf][(wr * 64 + mi * 16 + lrow) * BK + ko];
#pragma unroll
        for (int ni = 0; ni < 4; ++ni)
            bfrag[ni] = *(const s16x8*)&Bs[buf][(wc * 64 + ni * 16 + lrow) * BK + ko];

        __builtin_amdgcn_s_setprio(1);
#pragma unroll
        for (int mi = 0; mi < 4; ++mi)
#pragma unroll
            for (int ni = 0; ni < 4; ++ni)
                acc[mi][ni] = __builtin_amdgcn_mfma_f32_16x16x32_bf16(
                    afrag[mi], bfrag[ni], acc[mi][ni], 0, 0, 0);
        __builtin_amdgcn_s_setprio(0);

        // ensure this wave's LDS reads have sampled LDS before anyone restages this buffer
        asm volatile("s_waitcnt lgkmcnt(0)" ::: "memory");
        __builtin_amdgcn_s_barrier();

        if (kt + 2 < NKT) stage(kt + 2, buf);
    }

    // epilogue: exp, mask diag, row partial sums + (off-diag) col partial sums
    float part[4][4];   // [mi][r] row partials
    float colpart[4];   // [ni] col partials
#pragma unroll
    for (int mi = 0; mi < 4; mi++)
#pragma unroll
        for (int r = 0; r < 4; r++) part[mi][r] = 0.f;
#pragma unroll
    for (int ni = 0; ni < 4; ni++) colpart[ni] = 0.f;

    int rquad = (lane >> 4) * 4;
    int lcol = lane & 15;
#pragma unroll
    for (int mi = 0; mi < 4; mi++) {
#pragma unroll
        for (int ni = 0; ni < 4; ni++) {
            int gcol = colBase + wc * 64 + ni * 16 + lcol;
#pragma unroll
            for (int r = 0; r < 4; r++) {
                int grow = rowBase + wr * 64 + mi * 16 + rquad + r;
                float e = __expf(acc[mi][ni][r]);
                if (grow == gcol) e = 0.f;  // only possible when isDiag
                part[mi][r] += e;
                colpart[ni] += e;
            }
        }
    }

    // row reduce over lcol (xor 1,2,4,8), atomicAdd per row
#pragma unroll
    for (int m = 1; m < 16; m <<= 1) {
#pragma unroll
        for (int mi = 0; mi < 4; mi++)
#pragma unroll
            for (int r = 0; r < 4; r++) part[mi][r] += __shfl_xor(part[mi][r], m, 64);
    }
    if (lcol == 0) {
#pragma unroll
        for (int mi = 0; mi < 4; mi++)
#pragma unroll
            for (int r = 0; r < 4; r++) {
                int grow = rowBase + wr * 64 + mi * 16 + rquad + r;
                atomicAdd(&denomsum[grow], part[mi][r]);
            }
    }

    // col reduce over lane-groups (xor 16,32), atomicAdd per col — off-diag only
    if (!isDiag) {
#pragma unroll
        for (int ni = 0; ni < 4; ni++) {
            colpart[ni] += __shfl_xor(colpart[ni], 16, 64);
            colpart[ni] += __shfl_xor(colpart[ni], 32, 64);
        }
        if (lane < 16) {
#pragma unroll
            for (int ni = 0; ni < 4; ni++) {
                int gcol = colBase + wc * 64 + ni * 16 + lane;
                atomicAdd(&denomsum[gcol], colpart[ni]);
            }
        }
    }
}

// K4: finalize scalar loss
__global__ __launch_bounds__(256) void finalize_kernel(const int* __restrict__ labels,
                                                       const float* __restrict__ denomsum,
                                                       const float* __restrict__ selfdot,
                                                       const float* __restrict__ rawpos,
                                                       float* __restrict__ out) {
    __shared__ int nnorm_sh;
    __shared__ float tot_sh;
    int tid = threadIdx.x;
    if (tid == 0) {
        nnorm_sh = 0;
        tot_sh = 0.f;
    }
    __syncthreads();
    int c = 0;
    for (int j = tid; j < B; j += 256) c += (labels[j] == 0) ? 1 : 0;
    atomicAdd(&nnorm_sh, c);
    __syncthreads();
    int n_normal = nnorm_sh;
    float local = 0.f;
    for (int i = tid; i < B; i += 256) {
        if (labels[i] == 0) {
            int cntp = n_normal - 1;
            float rl = 0.f;
            if (cntp > 0) {
                float possum = rawpos[i] - selfdot[i];
                rl = logf(denomsum[i]) - possum / (float)cntp;
            }
            local += rl;
        }
    }
    atomicAdd(&tot_sh, local);
    __syncthreads();
    if (tid == 0) out[0] = (n_normal > 0) ? tot_sh / (float)n_normal : 0.f;
}

extern "C" void kernel_launch(void* const* d_in, const int* in_sizes, int n_in,
                              void* d_out, int out_size, void* d_ws, size_t ws_size,
                              hipStream_t stream) {
    const float* E = (const float*)d_in[0];
    const int* labels = (const int*)d_in[1];
    float* out = (float*)d_out;

    char* ws = (char*)d_ws;
    size_t off = 0;
    unsigned short* Ebf = (unsigned short*)(ws + off);
    off += (size_t)B * D * 2;  // 8 MB
    float* s = (float*)(ws + off);
    off += D * sizeof(float);  // 4 KB
    float* selfdot = (float*)(ws + off);
    off += B * sizeof(float);  // 16 KB
    float* rawpos = (float*)(ws + off);
    off += B * sizeof(float);  // 16 KB
    float* denomsum = (float*)(ws + off);
    off += B * sizeof(float);  // 16 KB
    float* partial = (float*)(ws + off);
    off += (size_t)CS_BLOCKS * D * sizeof(float);  // 1 MB

    prep_kernel<<<CS_BLOCKS, 256, 0, stream>>>(E, labels, Ebf, partial);
    colsum_reduce_kernel<<<D / 256, 256, 0, stream>>>(partial, s, denomsum);
    rowstats_kernel<<<B / 4, 256, 0, stream>>>(E, s, selfdot, rawpos);
    simexp_sym_kernel<<<NTRI, 256, 0, stream>>>(Ebf, denomsum);
    finalize_kernel<<<1, 256, 0, stream>>>(labels, denomsum, selfdot, rawpos, out);
}

// Round 5
// 80.335 us; speedup vs baseline: 1.1808x; 1.1808x over previous
//
#include <hip/hip_runtime.h>
#include <hip/hip_bf16.h>
#include <math.h>

#define B 4096
#define D 1024

// ---- 8-phase 256^2 simexp geometry ----
#define BM2 256
#define BK2 64
#define NK2 (D / BK2)   // 16 K-tiles
#define NB2 (B / BM2)   // 16 -> grid 256 blocks

#define CS_BLOCKS 256
#define CS_ROWS (B / CS_BLOCKS)  // 16

typedef float f32x4 __attribute__((ext_vector_type(4)));
typedef short s16x8 __attribute__((ext_vector_type(8)));

__device__ inline void gload_lds16(const void* g, void* l) {
    __builtin_amdgcn_global_load_lds(
        (const __attribute__((address_space(1))) void*)g,
        (__attribute__((address_space(3))) void*)l, 16, 0, 0);
}

// K0: fused fp32->bf16 convert + label-masked partial column sums.
__global__ __launch_bounds__(256) void prep_kernel(const float* __restrict__ E,
                                                   const int* __restrict__ labels,
                                                   unsigned short* __restrict__ Ebf,
                                                   float* __restrict__ partial) {
    int tid = threadIdx.x;
    int b = blockIdx.x;
    float4 acc = {0.f, 0.f, 0.f, 0.f};
    int r0 = b * CS_ROWS;
#pragma unroll 4
    for (int j = r0; j < r0 + CS_ROWS; ++j) {
        float4 v = *(const float4*)(E + (size_t)j * D + tid * 4);
        __hip_bfloat16 b0 = __float2bfloat16(v.x);
        __hip_bfloat16 b1 = __float2bfloat16(v.y);
        __hip_bfloat16 b2 = __float2bfloat16(v.z);
        __hip_bfloat16 b3 = __float2bfloat16(v.w);
        ushort4 o;
        o.x = *reinterpret_cast<unsigned short*>(&b0);
        o.y = *reinterpret_cast<unsigned short*>(&b1);
        o.z = *reinterpret_cast<unsigned short*>(&b2);
        o.w = *reinterpret_cast<unsigned short*>(&b3);
        *reinterpret_cast<ushort4*>(&Ebf[(size_t)j * D + tid * 4]) = o;
        if (labels[j] == 0) {
            acc.x += v.x;
            acc.y += v.y;
            acc.z += v.z;
            acc.w += v.w;
        }
    }
    *(float4*)(partial + (size_t)b * D + tid * 4) = acc;
}

// K1: reduce partials -> s[d]; also zero denomsum.
__global__ __launch_bounds__(256) void colsum_reduce_kernel(const float* __restrict__ partial,
                                                            float* __restrict__ s,
                                                            float* __restrict__ denomsum) {
    int d = blockIdx.x * 256 + threadIdx.x;
    float acc = 0.f;
    for (int p = 0; p < CS_BLOCKS; ++p) acc += partial[(size_t)p * D + d];
    s[d] = acc;
    for (int i = d; i < B; i += D) denomsum[i] = 0.f;
}

// K2: per-row selfdot = <e_i,e_i>, rawpos = <e_i, s>
__global__ __launch_bounds__(256) void rowstats_kernel(const float* __restrict__ E,
                                                       const float* __restrict__ s,
                                                       float* __restrict__ selfdot,
                                                       float* __restrict__ rawpos) {
    int wave = threadIdx.x >> 6;
    int lane = threadIdx.x & 63;
    int row = blockIdx.x * 4 + wave;
    const float4* er = (const float4*)(E + (size_t)row * D);
    const float4* s4 = (const float4*)s;
    float sd = 0.f, pp = 0.f;
    for (int it = 0; it < D / 4 / 64; ++it) {
        int k4 = it * 64 + lane;
        float4 v = er[k4];
        float4 w = s4[k4];
        sd += v.x * v.x + v.y * v.y + v.z * v.z + v.w * v.w;
        pp += v.x * w.x + v.y * w.y + v.z * w.z + v.w * w.w;
    }
    for (int m = 32; m; m >>= 1) {
        sd += __shfl_xor(sd, m, 64);
        pp += __shfl_xor(pp, m, 64);
    }
    if (lane == 0) {
        selfdot[row] = sd;
        rawpos[row] = pp;
    }
}

// MFMA quadrant: AH selects A rows (0: mi 0-3, 1: mi 4-7), NIH selects B cols half.
template <int AH, int NIH>
__device__ inline void doQ(f32x4 acc[8][4], const s16x8 aq[4][2], const s16x8 bq[2][2][2]) {
    __builtin_amdgcn_s_setprio(1);
#pragma unroll
    for (int mi = 0; mi < 4; ++mi)
#pragma unroll
        for (int ni = 0; ni < 2; ++ni)
#pragma unroll
            for (int ks = 0; ks < 2; ++ks)
                acc[AH * 4 + mi][NIH * 2 + ni] = __builtin_amdgcn_mfma_f32_16x16x32_bf16(
                    aq[mi][ks], bq[NIH][ni][ks], acc[AH * 4 + mi][NIH * 2 + ni], 0, 0, 0);
    __builtin_amdgcn_s_setprio(0);
}

// K3: 256^2 8-phase simexp. denomsum[i] += sum_j exp(<e_i,e_j>), diag masked.
// LDS halves: 0=A rows 0-127, 1=A rows 128-255, 2=B rows 0-127, 3=B rows 128-255.
// Swizzle: 16B-chunk p within a 128B row holds logical chunk p^(row&7); applied
// to the global source of global_load_lds (write side) and ds_read addr (read side).
__global__ __launch_bounds__(512, 2) void simexp8_kernel(const unsigned short* __restrict__ Ebf,
                                                         float* __restrict__ denomsum) {
    __shared__ short lds[2][4][128 * 64];  // 128 KiB
    const int tid = threadIdx.x;
    const int lane = tid & 63;
    const int wave = tid >> 6;  // 0..7
    const int wm = wave >> 2;   // 0..1  (M half)
    const int wn = wave & 3;    // 0..3  (N quarter)
    const int kh = lane >> 4;   // 0..3
    const int lrow = lane & 15;
    const int bi = blockIdx.x >> 4;
    const int bj = blockIdx.x & 15;
    const int rowBase = bi * BM2;
    const int colBase = bj * BM2;

    const short* gbase = (const short*)Ebf;

    // stage half h of K-tile kt into buf (2 x global_load_lds per thread)
    auto stage = [&](int kt, int buf, int h) {
        int gr0 = (h < 2 ? rowBase : colBase) + ((h & 1) ? 128 : 0);
#pragma unroll
        for (int q = 0; q < 2; ++q) {
            int i = q * 512 + tid;  // 16B chunk index in half (0..1023)
            int r = i >> 3;         // row in half
            int lc = (i & 7) ^ (r & 7);  // logical chunk for this physical slot
            const short* g = gbase + (size_t)(gr0 + r) * D + kt * BK2 + lc * 8;
            gload_lds16(g, &lds[buf][h][i * 8]);
        }
    };

    auto ldA = [&](int buf, int ah, s16x8 (&a)[4][2]) {
#pragma unroll
        for (int mi = 0; mi < 4; ++mi)
#pragma unroll
            for (int ks = 0; ks < 2; ++ks) {
                int rh = ah * 64 + mi * 16 + lrow;
                int c = ks * 4 + kh;
                a[mi][ks] = *(const s16x8*)&lds[buf][wm][rh * 64 + ((c ^ (rh & 7)) << 3)];
            }
    };
    auto ldB = [&](int buf, int nih, s16x8 (&bf)[2][2]) {
        int h = 2 + (wn >> 1);
#pragma unroll
        for (int ni = 0; ni < 2; ++ni)
#pragma unroll
            for (int ks = 0; ks < 2; ++ks) {
                int rh = (wn & 1) * 64 + nih * 32 + ni * 16 + lrow;
                int c = ks * 4 + kh;
                bf[ni][ks] = *(const s16x8*)&lds[buf][h][rh * 64 + ((c ^ (rh & 7)) << 3)];
            }
    };

    f32x4 acc[8][4];
#pragma unroll
    for (int i = 0; i < 8; ++i)
#pragma unroll
        for (int j = 0; j < 4; ++j) acc[i][j] = (f32x4)(0.f);

    s16x8 aq[4][2];
    s16x8 bq[2][2][2];

    // prologue: tile0 fully + tile1.A_lo (10 loads); wait tile0 (2 may fly)
    stage(0, 0, 0);
    stage(0, 0, 1);
    stage(0, 0, 2);
    stage(0, 0, 3);
    stage(1, 1, 0);
    asm volatile("s_waitcnt vmcnt(2)" ::: "memory");
    __builtin_amdgcn_s_barrier();

    for (int t = 0; t < NK2; ++t) {
        const int buf = t & 1;
        // ---- P1: read A-q0 (8) + B-q0 (4); stage (t+1).A_hi ----
        ldA(buf, 0, aq);
        ldB(buf, 0, bq[0]);
        if (t + 1 < NK2) stage(t + 1, buf ^ 1, 1);
        __builtin_amdgcn_s_barrier();
        asm volatile("s_waitcnt lgkmcnt(0)" ::: "memory");
        __builtin_amdgcn_sched_barrier(0);
        doQ<0, 0>(acc, aq, bq);
        __builtin_amdgcn_s_barrier();
        // ---- P2: read B-q1 (4); stage (t+1).B_lo ----
        ldB(buf, 1, bq[1]);
        if (t + 1 < NK2) stage(t + 1, buf ^ 1, 2);
        __builtin_amdgcn_s_barrier();
        asm volatile("s_waitcnt lgkmcnt(0)" ::: "memory");
        __builtin_amdgcn_sched_barrier(0);
        doQ<0, 1>(acc, aq, bq);
        __builtin_amdgcn_s_barrier();
        // ---- P3: read A-q1 (8); stage (t+1).B_hi ----
        ldA(buf, 1, aq);
        if (t + 1 < NK2) stage(t + 1, buf ^ 1, 3);
        __builtin_amdgcn_s_barrier();
        asm volatile("s_waitcnt lgkmcnt(0)" ::: "memory");
        __builtin_amdgcn_sched_barrier(0);
        doQ<1, 1>(acc, aq, bq);
        __builtin_amdgcn_s_barrier();
        // ---- P4: stage (t+2).A_lo; reuse regs; counted vmcnt ----
        if (t + 2 < NK2) stage(t + 2, buf, 0);
        __builtin_amdgcn_s_barrier();
        doQ<1, 0>(acc, aq, bq);
        if (t + 2 < NK2) {
            asm volatile("s_waitcnt vmcnt(2)" ::: "memory");  // t+1 halves done; t+2.A_lo may fly
        } else if (t + 1 < NK2) {
            asm volatile("s_waitcnt vmcnt(0)" ::: "memory");  // tail drain (t=14)
        }
        __builtin_amdgcn_s_barrier();
    }

    // epilogue: exp, diag mask, row-sum reduce over lrow, atomicAdd per row
#pragma unroll
    for (int mi = 0; mi < 8; ++mi) {
        float rs[4] = {0.f, 0.f, 0.f, 0.f};
#pragma unroll
        for (int ni = 0; ni < 4; ++ni) {
            int gcol = colBase + wn * 64 + ni * 16 + lrow;
#pragma unroll
            for (int r = 0; r < 4; ++r) {
                int grow = rowBase + wm * 128 + mi * 16 + kh * 4 + r;
                float e = __expf(acc[mi][ni][r]);
                if (grow == gcol) e = 0.f;  // diagonal (only when bi==bj)
                rs[r] += e;
            }
        }
#pragma unroll
        for (int m = 1; m < 16; m <<= 1)
#pragma unroll
            for (int r = 0; r < 4; ++r) rs[r] += __shfl_xor(rs[r], m, 64);
        if (lrow == 0) {
#pragma unroll
            for (int r = 0; r < 4; ++r)
                atomicAdd(&denomsum[rowBase + wm * 128 + mi * 16 + kh * 4 + r], rs[r]);
        }
    }
}

// K4: finalize scalar loss
__global__ __launch_bounds__(256) void finalize_kernel(const int* __restrict__ labels,
                                                       const float* __restrict__ denomsum,
                                                       const float* __restrict__ selfdot,
                                                       const float* __restrict__ rawpos,
                                                       float* __restrict__ out) {
    __shared__ int nnorm_sh;
    __shared__ float tot_sh;
    int tid = threadIdx.x;
    if (tid == 0) {
        nnorm_sh = 0;
        tot_sh = 0.f;
    }
    __syncthreads();
    int c = 0;
    for (int j = tid; j < B; j += 256) c += (labels[j] == 0) ? 1 : 0;
    atomicAdd(&nnorm_sh, c);
    __syncthreads();
    int n_normal = nnorm_sh;
    float local = 0.f;
    for (int i = tid; i < B; i += 256) {
        if (labels[i] == 0) {
            int cntp = n_normal - 1;
            float rl = 0.f;
            if (cntp > 0) {
                float possum = rawpos[i] - selfdot[i];
                rl = logf(denomsum[i]) - possum / (float)cntp;
            }
            local += rl;
        }
    }
    atomicAdd(&tot_sh, local);
    __syncthreads();
    if (tid == 0) out[0] = (n_normal > 0) ? tot_sh / (float)n_normal : 0.f;
}

extern "C" void kernel_launch(void* const* d_in, const int* in_sizes, int n_in,
                              void* d_out, int out_size, void* d_ws, size_t ws_size,
                              hipStream_t stream) {
    const float* E = (const float*)d_in[0];
    const int* labels = (const int*)d_in[1];
    float* out = (float*)d_out;

    char* ws = (char*)d_ws;
    size_t off = 0;
    unsigned short* Ebf = (unsigned short*)(ws + off);
    off += (size_t)B * D * 2;  // 8 MB
    float* s = (float*)(ws + off);
    off += D * sizeof(float);
    float* selfdot = (float*)(ws + off);
    off += B * sizeof(float);
    float* rawpos = (float*)(ws + off);
    off += B * sizeof(float);
    float* denomsum = (float*)(ws + off);
    off += B * sizeof(float);
    float* partial = (float*)(ws + off);
    off += (size_t)CS_BLOCKS * D * sizeof(float);

    prep_kernel<<<CS_BLOCKS, 256, 0, stream>>>(E, labels, Ebf, partial);
    colsum_reduce_kernel<<<D / 256, 256, 0, stream>>>(partial, s, denomsum);
    rowstats_kernel<<<B / 4, 256, 0, stream>>>(E, s, selfdot, rawpos);
    simexp8_kernel<<<NB2 * NB2, 512, 0, stream>>>(Ebf, denomsum);
    finalize_kernel<<<1, 256, 0, stream>>>(labels, denomsum, selfdot, rawpos, out);
}

// Round 6
// 56.114 us; speedup vs baseline: 1.6904x; 1.4316x over previous
//
#include <hip/hip_runtime.h>
#include <hip/hip_bf16.h>
#include <math.h>

#define B 4096
#define D 1024

// ---- 8-phase 256^2 simexp geometry ----
#define BM2 256
#define BK2 64
#define NK2 (D / BK2)   // 16 K-tiles
#define NB2 (B / BM2)   // 16 -> grid 256 blocks

typedef float f32x4 __attribute__((ext_vector_type(4)));
typedef short s16x8 __attribute__((ext_vector_type(8)));

__device__ inline void gload_lds16(const void* g, void* l) {
    __builtin_amdgcn_global_load_lds(
        (const __attribute__((address_space(1))) void*)g,
        (__attribute__((address_space(3))) void*)l, 16, 0, 0);
}

// K0: fp32 -> bf16 convert; also zero denomsum/lblsum accumulators.
__global__ __launch_bounds__(256) void prep_kernel(const float* __restrict__ E,
                                                   unsigned short* __restrict__ Ebf,
                                                   float* __restrict__ denomsum,
                                                   float* __restrict__ lblsum) {
    int idx = blockIdx.x * 256 + threadIdx.x;
    if (blockIdx.x < 16) denomsum[idx] = 0.f;
    else if (blockIdx.x < 32) lblsum[idx - 4096] = 0.f;
    const float4* src = (const float4*)E;
    const int n4 = B * D / 4;
    for (int i = idx; i < n4; i += gridDim.x * 256) {
        float4 v = src[i];
        __hip_bfloat16 b0 = __float2bfloat16(v.x);
        __hip_bfloat16 b1 = __float2bfloat16(v.y);
        __hip_bfloat16 b2 = __float2bfloat16(v.z);
        __hip_bfloat16 b3 = __float2bfloat16(v.w);
        ushort4 o;
        o.x = *reinterpret_cast<unsigned short*>(&b0);
        o.y = *reinterpret_cast<unsigned short*>(&b1);
        o.z = *reinterpret_cast<unsigned short*>(&b2);
        o.w = *reinterpret_cast<unsigned short*>(&b3);
        *reinterpret_cast<ushort4*>(&Ebf[i * 4]) = o;
    }
}

// MFMA quadrant: AH selects A rows half, NIH selects B cols half.
template <int AH, int NIH>
__device__ inline void doQ(f32x4 acc[8][4], const s16x8 aq[4][2], const s16x8 bq[2][2][2]) {
    __builtin_amdgcn_s_setprio(1);
#pragma unroll
    for (int mi = 0; mi < 4; ++mi)
#pragma unroll
        for (int ni = 0; ni < 2; ++ni)
#pragma unroll
            for (int ks = 0; ks < 2; ++ks)
                acc[AH * 4 + mi][NIH * 2 + ni] = __builtin_amdgcn_mfma_f32_16x16x32_bf16(
                    aq[mi][ks], bq[NIH][ni][ks], acc[AH * 4 + mi][NIH * 2 + ni], 0, 0, 0);
    __builtin_amdgcn_s_setprio(0);
}

// K1: 256^2 8-phase simexp.
//   denomsum[i] += sum_j exp(sim[i,j])   (diag masked)
//   lblsum[i]   += sum_j sim[i,j] * [label_j == 0]   (diag INCLUDED)
//   selfsim[i]   = sim[i,i]              (written by diagonal blocks)
// LDS halves: 0=A rows 0-127, 1=A rows 128-255, 2=B rows 0-127, 3=B rows 128-255.
// XOR chunk swizzle applied to global source (write side) and ds_read addr (read side).
// Stage schedule per tile u: P1:(u+1).A_lo  P2:(u+1).A_hi  P3:(u+2).B_lo  P4:(u+2).B_hi
//   (B halves are last read in P2, A halves in P3 -> each slot staged after its last reader.)
// One counted vmcnt(4) per tile at P4; drains to 0 only at u=14.
__global__ __launch_bounds__(512, 2) void simexp8_kernel(const unsigned short* __restrict__ Ebf,
                                                         const int* __restrict__ labels,
                                                         float* __restrict__ denomsum,
                                                         float* __restrict__ lblsum,
                                                         float* __restrict__ selfsim) {
    __shared__ short lds[2][4][128 * 64];  // 128 KiB
    const int tid = threadIdx.x;
    const int lane = tid & 63;
    const int wave = tid >> 6;  // 0..7
    const int wm = wave >> 2;   // 0..1  (M half)
    const int wn = wave & 3;    // 0..3  (N quarter)
    const int kh = lane >> 4;   // 0..3
    const int lrow = lane & 15;
    const int bi = blockIdx.x >> 4;
    const int bj = blockIdx.x & 15;
    const int rowBase = bi * BM2;
    const int colBase = bj * BM2;

    const short* gbase = (const short*)Ebf;

    // stage half h of K-tile kt into buf (2 x global_load_lds per thread)
    auto stage = [&](int kt, int buf, int h) {
        int gr0 = (h < 2 ? rowBase : colBase) + ((h & 1) ? 128 : 0);
#pragma unroll
        for (int q = 0; q < 2; ++q) {
            int i = q * 512 + tid;       // 16B chunk index in half (0..1023)
            int r = i >> 3;              // row in half
            int lc = (i & 7) ^ (r & 7);  // logical chunk for this physical slot
            const short* g = gbase + (size_t)(gr0 + r) * D + kt * BK2 + lc * 8;
            gload_lds16(g, &lds[buf][h][i * 8]);
        }
    };

    auto ldA = [&](int buf, int ah, s16x8 (&a)[4][2]) {
#pragma unroll
        for (int mi = 0; mi < 4; ++mi)
#pragma unroll
            for (int ks = 0; ks < 2; ++ks) {
                int rh = ah * 64 + mi * 16 + lrow;
                int c = ks * 4 + kh;
                a[mi][ks] = *(const s16x8*)&lds[buf][wm][rh * 64 + ((c ^ (rh & 7)) << 3)];
            }
    };
    auto ldB = [&](int buf, int nih, s16x8 (&bf)[2][2]) {
        int h = 2 + (wn >> 1);
#pragma unroll
        for (int ni = 0; ni < 2; ++ni)
#pragma unroll
            for (int ks = 0; ks < 2; ++ks) {
                int rh = (wn & 1) * 64 + nih * 32 + ni * 16 + lrow;
                int c = ks * 4 + kh;
                bf[ni][ks] = *(const s16x8*)&lds[buf][h][rh * 64 + ((c ^ (rh & 7)) << 3)];
            }
    };

    f32x4 acc[8][4];
#pragma unroll
    for (int i = 0; i < 8; ++i)
#pragma unroll
        for (int j = 0; j < 4; ++j) acc[i][j] = (f32x4)(0.f);

    s16x8 aq[4][2];
    s16x8 bq[2][2][2];

    // prologue: tile0 all 4 halves + tile1 B halves; wait tile0, leave tile1.B flying
    stage(0, 0, 0);
    stage(0, 0, 1);
    stage(0, 0, 2);
    stage(0, 0, 3);
    stage(1, 1, 2);
    stage(1, 1, 3);
    asm volatile("s_waitcnt vmcnt(4)" ::: "memory");
    __builtin_amdgcn_s_barrier();

    for (int u = 0; u < NK2; ++u) {
        const int bp = u & 1;
        // ---- P1: read A-q0 (8) + B-q0 (4); stage (u+1).A_lo ----
        ldA(bp, 0, aq);
        ldB(bp, 0, bq[0]);
        if (u + 1 < NK2) stage(u + 1, bp ^ 1, 0);
        __builtin_amdgcn_s_barrier();
        asm volatile("s_waitcnt lgkmcnt(0)" ::: "memory");
        __builtin_amdgcn_sched_barrier(0);
        doQ<0, 0>(acc, aq, bq);
        __builtin_amdgcn_s_barrier();
        // ---- P2: read B-q1 (4); stage (u+1).A_hi ----
        ldB(bp, 1, bq[1]);
        if (u + 1 < NK2) stage(u + 1, bp ^ 1, 1);
        __builtin_amdgcn_s_barrier();
        asm volatile("s_waitcnt lgkmcnt(0)" ::: "memory");
        __builtin_amdgcn_sched_barrier(0);
        doQ<0, 1>(acc, aq, bq);
        __builtin_amdgcn_s_barrier();
        // ---- P3: read A-q1 (8); stage (u+2).B_lo ----
        ldA(bp, 1, aq);
        if (u + 2 < NK2) stage(u + 2, bp, 2);
        __builtin_amdgcn_s_barrier();
        asm volatile("s_waitcnt lgkmcnt(0)" ::: "memory");
        __builtin_amdgcn_sched_barrier(0);
        doQ<1, 1>(acc, aq, bq);
        __builtin_amdgcn_s_barrier();
        // ---- P4 (reg-only MFMA): stage (u+2).B_hi; counted vmcnt; one barrier ----
        if (u + 2 < NK2) stage(u + 2, bp, 3);
        doQ<1, 0>(acc, aq, bq);
        if (u + 2 < NK2) {
            asm volatile("s_waitcnt vmcnt(4)" ::: "memory");  // (u+1) fully landed; (u+2).B_* fly
        } else if (u + 1 < NK2) {
            asm volatile("s_waitcnt vmcnt(0)" ::: "memory");  // tail drain (u=14)
        }
        __builtin_amdgcn_s_barrier();
    }

    // epilogue: exp + diag mask -> denomsum; label-masked sim row-sum -> lblsum;
    // diagonal sim -> selfsim.
    float lbm[4];
#pragma unroll
    for (int ni = 0; ni < 4; ++ni)
        lbm[ni] = (labels[colBase + wn * 64 + ni * 16 + lrow] == 0) ? 1.f : 0.f;

#pragma unroll
    for (int mi = 0; mi < 8; ++mi) {
        float rs[4] = {0.f, 0.f, 0.f, 0.f};
        float ps[4] = {0.f, 0.f, 0.f, 0.f};
#pragma unroll
        for (int ni = 0; ni < 4; ++ni) {
            int gcol = colBase + wn * 64 + ni * 16 + lrow;
#pragma unroll
            for (int r = 0; r < 4; ++r) {
                int grow = rowBase + wm * 128 + mi * 16 + kh * 4 + r;
                float sv = acc[mi][ni][r];
                float e = __expf(sv);
                if (grow == gcol) {
                    e = 0.f;
                    selfsim[grow] = sv;
                }
                rs[r] += e;
                ps[r] += sv * lbm[ni];
            }
        }
#pragma unroll
        for (int m = 1; m < 16; m <<= 1)
#pragma unroll
            for (int r = 0; r < 4; ++r) {
                rs[r] += __shfl_xor(rs[r], m, 64);
                ps[r] += __shfl_xor(ps[r], m, 64);
            }
        if (lrow == 0) {
#pragma unroll
            for (int r = 0; r < 4; ++r) {
                int grow = rowBase + wm * 128 + mi * 16 + kh * 4 + r;
                atomicAdd(&denomsum[grow], rs[r]);
                atomicAdd(&lblsum[grow], ps[r]);
            }
        }
    }
}

// K2: finalize scalar loss.
__global__ __launch_bounds__(1024) void finalize_kernel(const int* __restrict__ labels,
                                                        const float* __restrict__ denomsum,
                                                        const float* __restrict__ lblsum,
                                                        const float* __restrict__ selfsim,
                                                        float* __restrict__ out) {
    __shared__ int ncnt[16];
    __shared__ float tsum[16];
    int tid = threadIdx.x;
    int wv = tid >> 6, ln = tid & 63;

    int cnt = 0;
    for (int j = tid; j < B; j += 1024) cnt += (labels[j] == 0) ? 1 : 0;
    for (int m = 32; m; m >>= 1) cnt += __shfl_xor(cnt, m, 64);
    if (ln == 0) ncnt[wv] = cnt;
    __syncthreads();
    int n_normal = 0;
#pragma unroll
    for (int w = 0; w < 16; ++w) n_normal += ncnt[w];

    float local = 0.f;
    for (int i = tid; i < B; i += 1024) {
        if (labels[i] == 0) {
            int cntp = n_normal - 1;
            if (cntp > 0) {
                float possum = lblsum[i] - selfsim[i];  // remove j==i term (label_i==0 here)
                local += logf(denomsum[i]) - possum / (float)cntp;
            }
        }
    }
    for (int m = 32; m; m >>= 1) local += __shfl_xor(local, m, 64);
    if (ln == 0) tsum[wv] = local;
    __syncthreads();
    if (tid == 0) {
        float t = 0.f;
#pragma unroll
        for (int w = 0; w < 16; ++w) t += tsum[w];
        out[0] = (n_normal > 0) ? t / (float)n_normal : 0.f;
    }
}

extern "C" void kernel_launch(void* const* d_in, const int* in_sizes, int n_in,
                              void* d_out, int out_size, void* d_ws, size_t ws_size,
                              hipStream_t stream) {
    const float* E = (const float*)d_in[0];
    const int* labels = (const int*)d_in[1];
    float* out = (float*)d_out;

    char* ws = (char*)d_ws;
    size_t off = 0;
    unsigned short* Ebf = (unsigned short*)(ws + off);
    off += (size_t)B * D * 2;  // 8 MB
    float* denomsum = (float*)(ws + off);
    off += B * sizeof(float);
    float* lblsum = (float*)(ws + off);
    off += B * sizeof(float);
    float* selfsim = (float*)(ws + off);
    off += B * sizeof(float);

    prep_kernel<<<2048, 256, 0, stream>>>(E, Ebf, denomsum, lblsum);
    simexp8_kernel<<<NB2 * NB2, 512, 0, stream>>>(Ebf, labels, denomsum, lblsum, selfsim);
    finalize_kernel<<<1, 1024, 0, stream>>>(labels, denomsum, lblsum, selfsim, out);
}